// Round 1
// baseline (410.563 us; speedup 1.0000x reference)
//
#include <hip/hip_runtime.h>
#include <hip/hip_fp16.h>
#include <math.h>

#define L 4096
#define CDIM 256
#define DIN 512
#define DSTATE 16
#define DTR 16
#define BATCH 4

using f32x4  = __attribute__((ext_vector_type(4))) float;
using f16x8  = __attribute__((ext_vector_type(8))) _Float16;

__device__ __forceinline__ float silu_f(float x) { return x / (1.f + __expf(-x)); }
__device__ __forceinline__ float softplus_fast(float x) {
    return (x > 20.f) ? x : __logf(1.f + __expf(x));
}
__device__ __forceinline__ unsigned pk2h(float a, float b) {
    __half2 h = __floats2half2_rn(a, b);
    return *reinterpret_cast<unsigned*>(&h);
}
// lgkm-only barrier: drains ds_writes for cross-wave LDS visibility but leaves
// global register-loads in flight across the barrier (depth-2 prefetch lives on).
__device__ __forceinline__ void bar_lgkm() {
    asm volatile("s_waitcnt lgkmcnt(0)" ::: "memory");
    __builtin_amdgcn_s_barrier();
    __builtin_amdgcn_sched_barrier(0);
}

#define LDK 40

// ================= fp16 MFMA GEMM: 64-row tiles, LDS dbuf + depth-2 reg prefetch ===
// Out[b,m,n] = sum_k A*W. A fp16 row-major (or fp32 K-major for GEMM1).
// Block 64 x (2*NT*16); 4 waves 2x2; wave tile 32 x (NT*16). fp32 accumulate.
// k-loop (unrolled x2 so register-set index is compile-time):
//   sub-iter issues loads for kk+64 -> set s, MFMAs kk, stores kk+32 from set s^1.
//   Barrier is lgkm-only, so the kk+64 loads stay in flight a FULL iteration.
enum { HEPI_XP = 0, HEPI_UZ = 1, HEPI_F32 = 2, HEPI_D34 = 3 };
template<int EPI, bool A_F32KM, int NT>
__global__ __launch_bounds__(256)
void hgemm(const float* __restrict__ Af0, const float* __restrict__ Af1,
           const __half* __restrict__ Ah_g, const __half* __restrict__ Bh_g,
           const float* __restrict__ bias,
           float* __restrict__ O0, __half* __restrict__ Oh0, __half* __restrict__ Oh1,
           float* __restrict__ Ob, float* __restrict__ Oc,
           int M, int N, int K, int kSplit, long strideAb, int nBlk)
{
    constexpr int BM = 64, MT = 2;
    constexpr int BN = 2 * NT * 16;
    constexpr int BSEG = BN / 64;
    __shared__ __align__(16) _Float16 Ah[2][BM][LDK];
    __shared__ __align__(16) _Float16 Bh[2][BN][LDK];
    const int mBlk = M / BM;
    // XCD-sticky swizzle: n-blocks of one (b,m) A-tile share bid%8 -> same XCD L2
    const int bid = blockIdx.x;
    const int r = bid & 7, q = bid >> 3;
    const int ni = q % nBlk;
    const int mg = (q / nBlk) * 8 + r;
    const int b = mg / mBlk, m_idx = mg - b * mBlk;
    const int n0 = ni * BN, m0 = m_idx * BM;
    const int tid  = threadIdx.x;
    const int lane = tid & 63;
    const int w    = tid >> 6;
    const int wr   = w >> 1, wc = w & 1;
    const int lrow = lane & 15;
    const int loct = lane >> 4;

    f32x4 acc[MT][NT];
    #pragma unroll
    for (int i = 0; i < MT; ++i)
        #pragma unroll
        for (int j = 0; j < NT; ++j)
            acc[i][j] = (f32x4){0.f, 0.f, 0.f, 0.f};

    const int sOct = tid & 3, sRow = tid >> 2;   // A/B staging row + k-oct
    float va[2][8];
    uint4 pa[2], pb[2][BSEG];                    // two prefetch sets (literal idx only)

    auto loadA = [&](int kk, int s) {
        if (A_F32KM) {
            int m = tid & 63, ks = tid >> 6;      // 4 k-slices of 8
            #pragma unroll
            for (int j = 0; j < 8; ++j) {
                int kg = kk + ks * 8 + j;
                const float* Ap; int kl;
                if (kg < kSplit) { Ap = Af0; kl = kg; } else { Ap = Af1; kl = kg - kSplit; }
                va[s][j] = Ap[(long)b * strideAb + (long)kl * M + m0 + m];
            }
        } else {
            pa[s] = *(const uint4*)(Ah_g + (long)b * strideAb +
                                    (long)(m0 + sRow) * K + kk + sOct * 8);
        }
    };
    auto loadB = [&](int kk, int s) {
        #pragma unroll
        for (int p = 0; p < BSEG; ++p) {
            int ng = n0 + sRow + p * 64;
            if (EPI == HEPI_D34 && ng >= N)
                pb[s][p] = make_uint4(0, 0, 0, 0);
            else
                pb[s][p] = *(const uint4*)(Bh_g + (long)ng * K + kk + sOct * 8);
        }
    };
    auto storeAB = [&](int buf, int s) {
        if (A_F32KM) {
            int m = tid & 63, ks = tid >> 6;
            uint4 h;
            h.x = pk2h(va[s][0], va[s][1]);
            h.y = pk2h(va[s][2], va[s][3]);
            h.z = pk2h(va[s][4], va[s][5]);
            h.w = pk2h(va[s][6], va[s][7]);
            *(uint4*)&Ah[buf][m][ks * 8] = h;
        } else {
            *(uint4*)&Ah[buf][sRow][sOct * 8] = pa[s];
        }
        #pragma unroll
        for (int p = 0; p < BSEG; ++p)
            *(uint4*)&Bh[buf][sRow + p * 64][sOct * 8] = pb[s][p];
    };
    auto mfmaStep = [&](int cb) {
        f16x8 bh[NT];
        #pragma unroll
        for (int nt = 0; nt < NT; ++nt)
            bh[nt] = *(const f16x8*)&Bh[cb][wc*NT*16 + nt*16 + lrow][loct*8];
        #pragma unroll
        for (int mt = 0; mt < MT; ++mt) {
            f16x8 ah = *(const f16x8*)&Ah[cb][wr*MT*16 + mt*16 + lrow][loct*8];
            #pragma unroll
            for (int nt = 0; nt < NT; ++nt)
                acc[mt][nt] = __builtin_amdgcn_mfma_f32_16x16x32_f16(ah, bh[nt], acc[mt][nt], 0, 0, 0);
        }
    };

    // prologue: set0 -> LDS0; set1 in flight for kk=32 (all K here are multiples of 64, >=256)
    loadA(0, 0); loadB(0, 0);
    storeAB(0, 0);
    loadA(32, 1); loadB(32, 1);
    bar_lgkm();
    int cur = 0;
    for (int kk = 0; kk < K; kk += 64) {
        // sub-iter A: compute kk, prefetch kk+64 -> set0, store kk+32 (set1)
        if (kk + 64 < K) { loadA(kk + 64, 0); loadB(kk + 64, 0); }
        mfmaStep(cur);
        storeAB(cur ^ 1, 1);
        bar_lgkm();
        cur ^= 1;
        // sub-iter B: compute kk+32, prefetch kk+96 -> set1, store kk+64 (set0)
        if (kk + 96 < K) { loadA(kk + 96, 1); loadB(kk + 96, 1); }
        mfmaStep(cur);
        if (kk + 64 < K) {
            storeAB(cur ^ 1, 0);
            bar_lgkm();
            cur ^= 1;
        }
    }
    // epilogue: C/D col=lane&15, row=(lane>>4)*4+reg
    #pragma unroll
    for (int mt = 0; mt < MT; ++mt) {
        #pragma unroll
        for (int r4 = 0; r4 < 4; ++r4) {
            int m = m0 + wr*MT*16 + mt * 16 + loct * 4 + r4;
            long rowb = (long)b * M + m;
            #pragma unroll
            for (int nt = 0; nt < NT; ++nt) {
                int n = n0 + wc*NT*16 + nt * 16 + lrow;
                float v = acc[mt][nt][r4];
                if (EPI == HEPI_XP) {
                    Oh0[rowb * N + n] = __float2half(v + bias[n]);
                } else if (EPI == HEPI_UZ) {
                    if (n < DIN) Oh0[rowb * DIN + n] = __float2half(v);
                    else         Oh1[rowb * DIN + (n - DIN)] = __float2half(v);
                } else if (EPI == HEPI_D34) {
                    // rank-16 dbc outputs: dt raw (no bias/softplus), Bm, Cm
                    if (n < DTR)           O0[rowb * DTR + n] = v;
                    else if (n < 2 * DTR)  Ob[rowb * 16 + (n - DTR)] = v;
                    else if (n < 48)       Oc[rowb * 16 + (n - 32)] = v;
                } else {
                    O0[rowb * N + n] = v;
                }
            }
        }
    }
}

// ---------------- weight prep: fp16 casts (Wcomb fusion gone: dbc uses Wx direct) --
#define SZ_WP  131072
#define SZ_WIN 262144
#define SZ_WO  131072
#define SZ_WC  24576
__global__ __launch_bounds__(256)
void pack_all(const float* __restrict__ Wp, const float* __restrict__ Win,
              const float* __restrict__ Wout, const float* __restrict__ Wx,
              __half* __restrict__ wph, __half* __restrict__ winh,
              __half* __restrict__ woh, __half* __restrict__ wch)
{
    int i = blockIdx.x * 256 + threadIdx.x;
    if (i < SZ_WP) { wph[i] = __float2half(Wp[i]); return; }
    i -= SZ_WP;
    if (i < SZ_WIN) { winh[i] = __float2half(Win[i]); return; }
    i -= SZ_WIN;
    if (i < SZ_WO) { woh[i] = __float2half(Wout[i]); return; }
    i -= SZ_WO;
    if (i < SZ_WC) wch[i] = __float2half(Wx[i]);   // (48, 512) row-major
}

// ---------------- depthwise causal conv (k=4) + silu: fp16 in -> fp16 out ---------
__global__ __launch_bounds__(256)
void conv_silu_kernel(const __half* __restrict__ u_pre, const float* __restrict__ cw,
                      const float* __restrict__ cb, __half* __restrict__ u)
{
    long idx = (long)blockIdx.x * blockDim.x + threadIdx.x;
    int d = (int)(idx % DIN);
    long bl = idx / DIN;
    int l = (int)(bl % L);
    long brow = bl - l;
    float v = cb[d];
    #pragma unroll
    for (int j = 0; j < 4; ++j) {
        int li = l - 3 + j;
        if (li >= 0) v += __half2float(u_pre[(brow + li) * DIN + d]) * cw[d * 4 + j];
    }
    u[idx] = __float2half(silu_f(v));
}

// ---------------- chunked parallel selective scan, d-per-lane ----------------
// delta computed IN-SCAN: delta = softplus(dt . Wdt_row[d] + b_dt[d]), dt staged in LDS.
#define NC 128
#define LC (L / NC)

__global__ __launch_bounds__(256)
void scan_phase1(const float* __restrict__ dtA, const __half* __restrict__ u,
                 const float* __restrict__ Bm, const float* __restrict__ A_log,
                 const float* __restrict__ Wdt, const float* __restrict__ bdt,
                 float* __restrict__ Asum, float* __restrict__ Xsum)
{
    __shared__ float sB[LC][DSTATE];
    __shared__ float sDt[LC][DTR];
    const int gd = blockIdx.x & 1;
    const int c  = (blockIdx.x >> 1) & (NC - 1);
    const int b  = blockIdx.x >> 8;
    const int d  = gd * 256 + threadIdx.x;
    const int t0 = c * LC;
    float Arow[DSTATE];
    #pragma unroll
    for (int q = 0; q < 4; ++q) {
        float4 v = *(const float4*)&A_log[d * DSTATE + q * 4];
        Arow[q * 4 + 0] = -__expf(v.x);
        Arow[q * 4 + 1] = -__expf(v.y);
        Arow[q * 4 + 2] = -__expf(v.z);
        Arow[q * 4 + 3] = -__expf(v.w);
    }
    float Wrow[DTR];
    #pragma unroll
    for (int q = 0; q < 4; ++q) {
        float4 v = *(const float4*)&Wdt[d * DTR + q * 4];
        Wrow[q * 4 + 0] = v.x; Wrow[q * 4 + 1] = v.y;
        Wrow[q * 4 + 2] = v.z; Wrow[q * 4 + 3] = v.w;
    }
    const float bd = bdt[d];
    for (int i = threadIdx.x; i < LC * DSTATE; i += 256) {
        long row = (long)b * L + t0 + (i >> 4);
        sB[i >> 4][i & 15]  = Bm[row * DSTATE + (i & 15)];
        sDt[i >> 4][i & 15] = dtA[row * DTR + (i & 15)];
    }
    __syncthreads();
    float P[DSTATE], X[DSTATE];
    #pragma unroll
    for (int s = 0; s < DSTATE; ++s) { P[s] = 1.f; X[s] = 0.f; }
    for (int t = 0; t < LC; ++t) {
        long gidx = ((long)b * L + t0 + t) * DIN + d;
        float dp = bd;
        #pragma unroll
        for (int rr = 0; rr < DTR; ++rr) dp += sDt[t][rr] * Wrow[rr];
        float dlt = softplus_fast(dp);
        float du  = dlt * __half2float(u[gidx]);
        #pragma unroll
        for (int s = 0; s < DSTATE; ++s) {
            float a = __expf(dlt * Arow[s]);
            P[s] *= a;
            X[s] = a * X[s] + du * sB[t][s];
        }
    }
    long o = (((long)b * NC + c) * DIN + d) * DSTATE;
    #pragma unroll
    for (int q = 0; q < 4; ++q) {
        *(float4*)&Asum[o + q * 4] = make_float4(P[q*4], P[q*4+1], P[q*4+2], P[q*4+3]);
        *(float4*)&Xsum[o + q * 4] = make_float4(X[q*4], X[q*4+1], X[q*4+2], X[q*4+3]);
    }
}

__global__ __launch_bounds__(256)
void scan_phase2(const float* __restrict__ Asum, float* __restrict__ Xsum)
{
    int lane = blockIdx.x * 256 + threadIdx.x;
    int b = lane / (DIN * DSTATE);
    int rem = lane % (DIN * DSTATE);
    float h = 0.f;
    for (int c = 0; c < NC; ++c) {
        long idx = ((long)b * NC + c) * (DIN * DSTATE) + rem;
        float A = Asum[idx], X = Xsum[idx];
        Xsum[idx] = h;
        h = A * h + X;
    }
}

__global__ __launch_bounds__(256)
void scan_phase3(const float* __restrict__ dtA, const __half* __restrict__ u,
                 const float* __restrict__ Bm, const float* __restrict__ Cm,
                 const __half* __restrict__ z, const float* __restrict__ A_log,
                 const float* __restrict__ Wdt, const float* __restrict__ bdt,
                 const float* __restrict__ Dp, const float* __restrict__ Hinit,
                 __half* __restrict__ y2h)
{
    __shared__ float sB[LC][DSTATE], sC[LC][DSTATE];
    __shared__ float sDt[LC][DTR];
    const int gd = blockIdx.x & 1;
    const int c  = (blockIdx.x >> 1) & (NC - 1);
    const int b  = blockIdx.x >> 8;
    const int d  = gd * 256 + threadIdx.x;
    const int t0 = c * LC;
    float Arow[DSTATE];
    #pragma unroll
    for (int q = 0; q < 4; ++q) {
        float4 v = *(const float4*)&A_log[d * DSTATE + q * 4];
        Arow[q * 4 + 0] = -__expf(v.x);
        Arow[q * 4 + 1] = -__expf(v.y);
        Arow[q * 4 + 2] = -__expf(v.z);
        Arow[q * 4 + 3] = -__expf(v.w);
    }
    float Wrow[DTR];
    #pragma unroll
    for (int q = 0; q < 4; ++q) {
        float4 v = *(const float4*)&Wdt[d * DTR + q * 4];
        Wrow[q * 4 + 0] = v.x; Wrow[q * 4 + 1] = v.y;
        Wrow[q * 4 + 2] = v.z; Wrow[q * 4 + 3] = v.w;
    }
    const float bd = bdt[d];
    for (int i = threadIdx.x; i < LC * DSTATE; i += 256) {
        long row = (long)b * L + t0 + (i >> 4);
        long gidx = row * DSTATE + (i & 15);
        sB[i >> 4][i & 15]  = Bm[gidx];
        sC[i >> 4][i & 15]  = Cm[gidx];
        sDt[i >> 4][i & 15] = dtA[row * DTR + (i & 15)];
    }
    float h[DSTATE];
    {
        long o = (((long)b * NC + c) * DIN + d) * DSTATE;
        #pragma unroll
        for (int q = 0; q < 4; ++q) {
            float4 v = *(const float4*)&Hinit[o + q * 4];
            h[q * 4 + 0] = v.x; h[q * 4 + 1] = v.y;
            h[q * 4 + 2] = v.z; h[q * 4 + 3] = v.w;
        }
    }
    const float Dval = Dp[d];
    __syncthreads();
    for (int t = 0; t < LC; ++t) {
        long gidx = ((long)b * L + t0 + t) * DIN + d;
        float dp = bd;
        #pragma unroll
        for (int rr = 0; rr < DTR; ++rr) dp += sDt[t][rr] * Wrow[rr];
        float dlt = softplus_fast(dp);
        float uu  = __half2float(u[gidx]);
        float zz  = __half2float(z[gidx]);
        float du  = dlt * uu;
        float y = 0.f;
        #pragma unroll
        for (int s = 0; s < DSTATE; ++s) {
            float a = __expf(dlt * Arow[s]);
            h[s] = h[s] * a + du * sB[t][s];
            y += h[s] * sC[t][s];
        }
        y2h[gidx] = __float2half((y + uu * Dval) * silu_f(zz));
    }
}

// ---------------- LayerNorm over C + transpose to (B,C,L) ----------------
__global__ __launch_bounds__(256)
void ln_kernel(const float* __restrict__ X, const float* __restrict__ gamma,
               const float* __restrict__ beta, float* __restrict__ out)
{
    __shared__ float tile[32][257];
    __shared__ float sMu[32], sRs[32];
    const int l0 = blockIdx.x * 32;
    const int b  = blockIdx.y;
    const int tid = threadIdx.x;
    for (int i = tid; i < 32 * 256; i += 256) {
        int l = i >> 8, c = i & 255;
        tile[l][c] = X[((long)b * L + l0 + l) * CDIM + c];
    }
    __syncthreads();
    {
        int l = tid >> 3, sub = tid & 7;
        float s1 = 0.f, s2 = 0.f;
        for (int c = sub * 32; c < sub * 32 + 32; ++c) {
            float v = tile[l][c];
            s1 += v; s2 += v * v;
        }
        s1 += __shfl_xor(s1, 1); s2 += __shfl_xor(s2, 1);
        s1 += __shfl_xor(s1, 2); s2 += __shfl_xor(s2, 2);
        s1 += __shfl_xor(s1, 4); s2 += __shfl_xor(s2, 4);
        if (sub == 0) {
            float mu = s1 * (1.f / 256.f);
            float var = s2 * (1.f / 256.f) - mu * mu;
            sMu[l] = mu;
            sRs[l] = rsqrtf(var + 1e-5f);
        }
    }
    __syncthreads();
    for (int i = tid; i < 32 * 256; i += 256) {
        int ll = i & 31, c = i >> 5;
        float v = (tile[ll][c] - sMu[ll]) * sRs[ll] * gamma[c] + beta[c];
        out[((long)b * CDIM + c) * L + l0 + ll] = v;
    }
}

extern "C" void kernel_launch(void* const* d_in, const int* in_sizes, int n_in,
                              void* d_out, int out_size, void* d_ws, size_t ws_size,
                              hipStream_t stream)
{
    const float* sp   = (const float*)d_in[0];
    const float* fq   = (const float*)d_in[1];
    const float* Wp   = (const float*)d_in[2];
    const float* bp   = (const float*)d_in[3];
    const float* Win  = (const float*)d_in[4];
    const float* cw   = (const float*)d_in[5];
    const float* cb   = (const float*)d_in[6];
    const float* Wx   = (const float*)d_in[7];
    const float* Wdt  = (const float*)d_in[8];
    const float* bdt  = (const float*)d_in[9];
    const float* Alog = (const float*)d_in[10];
    const float* Dp   = (const float*)d_in[11];
    const float* Wout = (const float*)d_in[12];
    const float* gam  = (const float*)d_in[13];
    const float* bet  = (const float*)d_in[14];
    float* out = (float*)d_out;
    float* ws  = (float*)d_ws;

    const size_t NLD = (size_t)BATCH * L * DIN;   // 8.39M
    const size_t NLC = (size_t)BATCH * L * CDIM;  // 4.19M

    size_t off = 0;
    __half* u16   = (__half*)(ws + off); off += NLD / 2;  // pre-conv u
    __half* u16c  = (__half*)(ws + off); off += NLD / 2;  // post-conv silu(u)
    __half* z16   = (__half*)(ws + off); off += NLD / 2;
    __half* y16   = (__half*)(ws + off); off += NLD / 2;
    __half* xp16  = (__half*)(ws + off); off += NLC / 2;
    float*  xmix  = ws + off; off += NLC;
    float*  dtA   = ws + off; off += (size_t)BATCH * L * DTR;   // raw dt (fp32, 1 MB)
    __half* wph   = (__half*)(ws + off); off += SZ_WP / 2;
    __half* winh  = (__half*)(ws + off); off += SZ_WIN / 2;
    __half* woh   = (__half*)(ws + off); off += SZ_WO / 2;
    __half* wch   = (__half*)(ws + off); off += SZ_WC / 2;
    float*  Bmb   = ws + off; off += (size_t)BATCH * L * DSTATE;
    float*  Cmb   = ws + off; off += (size_t)BATCH * L * DSTATE;
    float*  Asum  = ws + off; off += (size_t)BATCH * NC * DIN * DSTATE;
    float*  Xsum  = ws + off; off += (size_t)BATCH * NC * DIN * DSTATE;

    dim3 blk(256);
    pack_all<<<dim3((SZ_WP + SZ_WIN + SZ_WO + SZ_WC) / 256), blk, 0, stream>>>(
        Wp, Win, Wout, Wx, wph, winh, woh, wch);

    // GEMM1 (fp16): x_proj = x_cat @ Wp^T + bp  (A fp32 K-major; BM=64, NT=2, nBlk=4)
    hgemm<HEPI_XP, true, 2><<<dim3(BATCH * (L/64) * 4), blk, 0, stream>>>(
        sp, fq, nullptr, wph, bp, nullptr, xp16, nullptr, nullptr, nullptr,
        L, CDIM, 2 * CDIM, CDIM, (long)CDIM * L, 4);
    // GEMM2 (fp16): xz = x_proj @ Win^T -> u16 / z16  (BM=64, NT=4, nBlk=8)
    hgemm<HEPI_UZ, false, 4><<<dim3(BATCH * (L/64) * 8), blk, 0, stream>>>(
        nullptr, nullptr, xp16, winh, nullptr, nullptr, u16, z16, nullptr, nullptr,
        L, 2 * DIN, CDIM, 1 << 30, (long)L * CDIM, 8);
    conv_silu_kernel<<<dim3((int)(NLD / 256)), blk, 0, stream>>>(u16, cw, cb, u16c);
    // D34 rank-16 form: dbc = u @ Wx^T (N=48 only: dt|Bm|Cm). delta folded into scans.
    hgemm<HEPI_D34, false, 2><<<dim3(BATCH * (L/64) * 1), blk, 0, stream>>>(
        nullptr, nullptr, u16c, wch, nullptr, dtA, nullptr, nullptr, Bmb, Cmb,
        L, 48, DIN, 1 << 30, (long)L * DIN, 1);

    scan_phase1<<<dim3(BATCH * NC * 2), blk, 0, stream>>>(
        dtA, u16c, Bmb, Alog, Wdt, bdt, Asum, Xsum);
    scan_phase2<<<dim3(BATCH * DIN * DSTATE / 256), blk, 0, stream>>>(Asum, Xsum);
    scan_phase3<<<dim3(BATCH * NC * 2), blk, 0, stream>>>(
        dtA, u16c, Bmb, Cmb, z16, Alog, Wdt, bdt, Dp, Xsum, y16);

    // GEMM5 (fp16): x_mixed = y2 @ Wout^T  (BM=64, NT=2, nBlk=4)
    hgemm<HEPI_F32, false, 2><<<dim3(BATCH * (L/64) * 4), blk, 0, stream>>>(
        nullptr, nullptr, y16, woh, nullptr, xmix, nullptr, nullptr, nullptr, nullptr,
        L, CDIM, DIN, 1 << 30, (long)L * DIN, 4);
    ln_kernel<<<dim3(L / 32, BATCH), blk, 0, stream>>>(xmix, gam, bet, out);
}

// Round 2
// 344.102 us; speedup vs baseline: 1.1931x; 1.1931x over previous
//
#include <hip/hip_runtime.h>
#include <hip/hip_fp16.h>
#include <math.h>

#define L 4096
#define CDIM 256
#define DIN 512
#define DSTATE 16
#define DTR 16
#define BATCH 4

using f32x4  = __attribute__((ext_vector_type(4))) float;
using f16x8  = __attribute__((ext_vector_type(8))) _Float16;

__device__ __forceinline__ float silu_f(float x) { return x / (1.f + __expf(-x)); }
__device__ __forceinline__ float softplus_fast(float x) {
    return (x > 20.f) ? x : __logf(1.f + __expf(x));
}
__device__ __forceinline__ unsigned pk2h(float a, float b) {
    __half2 h = __floats2half2_rn(a, b);
    return *reinterpret_cast<unsigned*>(&h);
}

#define LDK 40

// ================= fp16 MFMA GEMM: 64-row tiles, double-buffered single-barrier ====
// Out[b,m,n] = sum_k A*W. A fp16 row-major (or fp32 K-major for GEMM1).
// Block 64 x (2*NT*16); 4 waves 2x2; wave tile 32 x (NT*16). fp32 accumulate.
// k-loop: load(kk+32) -> mfma buf[cur] -> store buf[cur^1] -> ONE barrier.
// (Round-0 schedule restored: measured-good. Depth-2 reg prefetch + lgkm-only
//  barrier experiment regressed: anomalous 181 MB WRITE_SIZE, MfmaUtil 6.6->4.4.)
enum { HEPI_XP = 0, HEPI_UZ = 1, HEPI_F32 = 2, HEPI_D34 = 3 };
template<int EPI, bool A_F32KM, int NT>
__global__ __launch_bounds__(256)
void hgemm(const float* __restrict__ Af0, const float* __restrict__ Af1,
           const __half* __restrict__ Ah_g, const __half* __restrict__ Bh_g,
           const float* __restrict__ bias,
           float* __restrict__ O0, __half* __restrict__ Oh0, __half* __restrict__ Oh1,
           float* __restrict__ Ob, float* __restrict__ Oc,
           int M, int N, int K, int kSplit, long strideAb, int nBlk)
{
    constexpr int BM = 64, MT = 2;
    constexpr int BN = 2 * NT * 16;
    constexpr int BSEG = BN / 64;
    __shared__ __align__(16) _Float16 Ah[2][BM][LDK];
    __shared__ __align__(16) _Float16 Bh[2][BN][LDK];
    const int mBlk = M / BM;
    // XCD-sticky swizzle: n-blocks of one (b,m) A-tile share bid%8 -> same XCD L2
    const int bid = blockIdx.x;
    const int r = bid & 7, q = bid >> 3;
    const int ni = q % nBlk;
    const int mg = (q / nBlk) * 8 + r;
    const int b = mg / mBlk, m_idx = mg - b * mBlk;
    const int n0 = ni * BN, m0 = m_idx * BM;
    const int tid  = threadIdx.x;
    const int lane = tid & 63;
    const int w    = tid >> 6;
    const int wr   = w >> 1, wc = w & 1;
    const int lrow = lane & 15;
    const int loct = lane >> 4;

    f32x4 acc[MT][NT];
    #pragma unroll
    for (int i = 0; i < MT; ++i)
        #pragma unroll
        for (int j = 0; j < NT; ++j)
            acc[i][j] = (f32x4){0.f, 0.f, 0.f, 0.f};

    const int sOct = tid & 3, sRow = tid >> 2;   // A/B staging row + k-oct
    float va[8];
    uint4 pa, pb[BSEG];

    auto loadA = [&](int kk) {
        if (A_F32KM) {
            int m = tid & 63, ks = tid >> 6;      // 4 k-slices of 8
            #pragma unroll
            for (int j = 0; j < 8; ++j) {
                int kg = kk + ks * 8 + j;
                const float* Ap; int kl;
                if (kg < kSplit) { Ap = Af0; kl = kg; } else { Ap = Af1; kl = kg - kSplit; }
                va[j] = Ap[(long)b * strideAb + (long)kl * M + m0 + m];
            }
        } else {
            pa = *(const uint4*)(Ah_g + (long)b * strideAb +
                                 (long)(m0 + sRow) * K + kk + sOct * 8);
        }
    };
    auto loadB = [&](int kk) {
        #pragma unroll
        for (int p = 0; p < BSEG; ++p) {
            int ng = n0 + sRow + p * 64;
            if (EPI == HEPI_D34 && ng >= N)
                pb[p] = make_uint4(0, 0, 0, 0);
            else
                pb[p] = *(const uint4*)(Bh_g + (long)ng * K + kk + sOct * 8);
        }
    };
    auto storeAB = [&](int buf) {
        if (A_F32KM) {
            int m = tid & 63, ks = tid >> 6;
            uint4 h;
            h.x = pk2h(va[0], va[1]);
            h.y = pk2h(va[2], va[3]);
            h.z = pk2h(va[4], va[5]);
            h.w = pk2h(va[6], va[7]);
            *(uint4*)&Ah[buf][m][ks * 8] = h;
        } else {
            *(uint4*)&Ah[buf][sRow][sOct * 8] = pa;
        }
        #pragma unroll
        for (int p = 0; p < BSEG; ++p)
            *(uint4*)&Bh[buf][sRow + p * 64][sOct * 8] = pb[p];
    };

    loadA(0); loadB(0);
    storeAB(0);
    __syncthreads();
    int cur = 0;
    for (int kk = 0; kk < K; kk += 32) {
        const bool more = (kk + 32 < K);
        if (more) { loadA(kk + 32); loadB(kk + 32); }   // in flight during MFMA
        f16x8 bh[NT];
        #pragma unroll
        for (int nt = 0; nt < NT; ++nt)
            bh[nt] = *(const f16x8*)&Bh[cur][wc*NT*16 + nt*16 + lrow][loct*8];
        #pragma unroll
        for (int mt = 0; mt < MT; ++mt) {
            f16x8 ah = *(const f16x8*)&Ah[cur][wr*MT*16 + mt*16 + lrow][loct*8];
            #pragma unroll
            for (int nt = 0; nt < NT; ++nt)
                acc[mt][nt] = __builtin_amdgcn_mfma_f32_16x16x32_f16(ah, bh[nt], acc[mt][nt], 0, 0, 0);
        }
        if (more) {
            storeAB(cur ^ 1);
            __syncthreads();        // ONE barrier per k-iter
            cur ^= 1;
        }
    }
    // epilogue: C/D col=lane&15, row=(lane>>4)*4+reg
    #pragma unroll
    for (int mt = 0; mt < MT; ++mt) {
        #pragma unroll
        for (int r4 = 0; r4 < 4; ++r4) {
            int m = m0 + wr*MT*16 + mt * 16 + loct * 4 + r4;
            long rowb = (long)b * M + m;
            #pragma unroll
            for (int nt = 0; nt < NT; ++nt) {
                int n = n0 + wc*NT*16 + nt * 16 + lrow;
                float v = acc[mt][nt][r4];
                if (EPI == HEPI_XP) {
                    Oh0[rowb * N + n] = __float2half(v + bias[n]);
                } else if (EPI == HEPI_UZ) {
                    if (n < DIN) Oh0[rowb * DIN + n] = __float2half(v);
                    else         Oh1[rowb * DIN + (n - DIN)] = __float2half(v);
                } else if (EPI == HEPI_D34) {
                    // rank-16 dbc outputs: dt raw (delta folded into scans), Bm, Cm
                    if (n < DTR)           O0[rowb * DTR + n] = v;
                    else if (n < 2 * DTR)  Ob[rowb * 16 + (n - DTR)] = v;
                    else if (n < 48)       Oc[rowb * 16 + (n - 32)] = v;
                } else {
                    O0[rowb * N + n] = v;
                }
            }
        }
    }
}

// ---------------- weight prep: fp16 casts (dbc uses Wx directly, rank-16) ---------
#define SZ_WP  131072
#define SZ_WIN 262144
#define SZ_WO  131072
#define SZ_WC  24576
__global__ __launch_bounds__(256)
void pack_all(const float* __restrict__ Wp, const float* __restrict__ Win,
              const float* __restrict__ Wout, const float* __restrict__ Wx,
              __half* __restrict__ wph, __half* __restrict__ winh,
              __half* __restrict__ woh, __half* __restrict__ wch)
{
    int i = blockIdx.x * 256 + threadIdx.x;
    if (i < SZ_WP) { wph[i] = __float2half(Wp[i]); return; }
    i -= SZ_WP;
    if (i < SZ_WIN) { winh[i] = __float2half(Win[i]); return; }
    i -= SZ_WIN;
    if (i < SZ_WO) { woh[i] = __float2half(Wout[i]); return; }
    i -= SZ_WO;
    if (i < SZ_WC) wch[i] = __float2half(Wx[i]);   // (48, 512) row-major
}

// ---------------- depthwise causal conv (k=4) + silu: fp16 in -> fp16 out ---------
__global__ __launch_bounds__(256)
void conv_silu_kernel(const __half* __restrict__ u_pre, const float* __restrict__ cw,
                      const float* __restrict__ cb, __half* __restrict__ u)
{
    long idx = (long)blockIdx.x * blockDim.x + threadIdx.x;
    int d = (int)(idx % DIN);
    long bl = idx / DIN;
    int l = (int)(bl % L);
    long brow = bl - l;
    float v = cb[d];
    #pragma unroll
    for (int j = 0; j < 4; ++j) {
        int li = l - 3 + j;
        if (li >= 0) v += __half2float(u_pre[(brow + li) * DIN + d]) * cw[d * 4 + j];
    }
    u[idx] = __float2half(silu_f(v));
}

// ---------------- chunked parallel selective scan, d-per-lane ----------------
// delta computed IN-SCAN: delta = softplus(dt . Wdt_row[d] + b_dt[d]), dt staged in LDS.
#define NC 128
#define LC (L / NC)

__global__ __launch_bounds__(256)
void scan_phase1(const float* __restrict__ dtA, const __half* __restrict__ u,
                 const float* __restrict__ Bm, const float* __restrict__ A_log,
                 const float* __restrict__ Wdt, const float* __restrict__ bdt,
                 float* __restrict__ Asum, float* __restrict__ Xsum)
{
    __shared__ float sB[LC][DSTATE];
    __shared__ float sDt[LC][DTR];
    const int gd = blockIdx.x & 1;
    const int c  = (blockIdx.x >> 1) & (NC - 1);
    const int b  = blockIdx.x >> 8;
    const int d  = gd * 256 + threadIdx.x;
    const int t0 = c * LC;
    float Arow[DSTATE];
    #pragma unroll
    for (int q = 0; q < 4; ++q) {
        float4 v = *(const float4*)&A_log[d * DSTATE + q * 4];
        Arow[q * 4 + 0] = -__expf(v.x);
        Arow[q * 4 + 1] = -__expf(v.y);
        Arow[q * 4 + 2] = -__expf(v.z);
        Arow[q * 4 + 3] = -__expf(v.w);
    }
    float Wrow[DTR];
    #pragma unroll
    for (int q = 0; q < 4; ++q) {
        float4 v = *(const float4*)&Wdt[d * DTR + q * 4];
        Wrow[q * 4 + 0] = v.x; Wrow[q * 4 + 1] = v.y;
        Wrow[q * 4 + 2] = v.z; Wrow[q * 4 + 3] = v.w;
    }
    const float bd = bdt[d];
    for (int i = threadIdx.x; i < LC * DSTATE; i += 256) {
        long row = (long)b * L + t0 + (i >> 4);
        sB[i >> 4][i & 15]  = Bm[row * DSTATE + (i & 15)];
        sDt[i >> 4][i & 15] = dtA[row * DTR + (i & 15)];
    }
    __syncthreads();
    float P[DSTATE], X[DSTATE];
    #pragma unroll
    for (int s = 0; s < DSTATE; ++s) { P[s] = 1.f; X[s] = 0.f; }
    for (int t = 0; t < LC; ++t) {
        long gidx = ((long)b * L + t0 + t) * DIN + d;
        float dp = bd;
        #pragma unroll
        for (int rr = 0; rr < DTR; ++rr) dp += sDt[t][rr] * Wrow[rr];
        float dlt = softplus_fast(dp);
        float du  = dlt * __half2float(u[gidx]);
        #pragma unroll
        for (int s = 0; s < DSTATE; ++s) {
            float a = __expf(dlt * Arow[s]);
            P[s] *= a;
            X[s] = a * X[s] + du * sB[t][s];
        }
    }
    long o = (((long)b * NC + c) * DIN + d) * DSTATE;
    #pragma unroll
    for (int q = 0; q < 4; ++q) {
        *(float4*)&Asum[o + q * 4] = make_float4(P[q*4], P[q*4+1], P[q*4+2], P[q*4+3]);
        *(float4*)&Xsum[o + q * 4] = make_float4(X[q*4], X[q*4+1], X[q*4+2], X[q*4+3]);
    }
}

__global__ __launch_bounds__(256)
void scan_phase2(const float* __restrict__ Asum, float* __restrict__ Xsum)
{
    int lane = blockIdx.x * 256 + threadIdx.x;
    int b = lane / (DIN * DSTATE);
    int rem = lane % (DIN * DSTATE);
    float h = 0.f;
    for (int c = 0; c < NC; ++c) {
        long idx = ((long)b * NC + c) * (DIN * DSTATE) + rem;
        float A = Asum[idx], X = Xsum[idx];
        Xsum[idx] = h;
        h = A * h + X;
    }
}

__global__ __launch_bounds__(256)
void scan_phase3(const float* __restrict__ dtA, const __half* __restrict__ u,
                 const float* __restrict__ Bm, const float* __restrict__ Cm,
                 const __half* __restrict__ z, const float* __restrict__ A_log,
                 const float* __restrict__ Wdt, const float* __restrict__ bdt,
                 const float* __restrict__ Dp, const float* __restrict__ Hinit,
                 __half* __restrict__ y2h)
{
    __shared__ float sB[LC][DSTATE], sC[LC][DSTATE];
    __shared__ float sDt[LC][DTR];
    const int gd = blockIdx.x & 1;
    const int c  = (blockIdx.x >> 1) & (NC - 1);
    const int b  = blockIdx.x >> 8;
    const int d  = gd * 256 + threadIdx.x;
    const int t0 = c * LC;
    float Arow[DSTATE];
    #pragma unroll
    for (int q = 0; q < 4; ++q) {
        float4 v = *(const float4*)&A_log[d * DSTATE + q * 4];
        Arow[q * 4 + 0] = -__expf(v.x);
        Arow[q * 4 + 1] = -__expf(v.y);
        Arow[q * 4 + 2] = -__expf(v.z);
        Arow[q * 4 + 3] = -__expf(v.w);
    }
    float Wrow[DTR];
    #pragma unroll
    for (int q = 0; q < 4; ++q) {
        float4 v = *(const float4*)&Wdt[d * DTR + q * 4];
        Wrow[q * 4 + 0] = v.x; Wrow[q * 4 + 1] = v.y;
        Wrow[q * 4 + 2] = v.z; Wrow[q * 4 + 3] = v.w;
    }
    const float bd = bdt[d];
    for (int i = threadIdx.x; i < LC * DSTATE; i += 256) {
        long row = (long)b * L + t0 + (i >> 4);
        long gidx = row * DSTATE + (i & 15);
        sB[i >> 4][i & 15]  = Bm[gidx];
        sC[i >> 4][i & 15]  = Cm[gidx];
        sDt[i >> 4][i & 15] = dtA[row * DTR + (i & 15)];
    }
    float h[DSTATE];
    {
        long o = (((long)b * NC + c) * DIN + d) * DSTATE;
        #pragma unroll
        for (int q = 0; q < 4; ++q) {
            float4 v = *(const float4*)&Hinit[o + q * 4];
            h[q * 4 + 0] = v.x; h[q * 4 + 1] = v.y;
            h[q * 4 + 2] = v.z; h[q * 4 + 3] = v.w;
        }
    }
    const float Dval = Dp[d];
    __syncthreads();
    for (int t = 0; t < LC; ++t) {
        long gidx = ((long)b * L + t0 + t) * DIN + d;
        float dp = bd;
        #pragma unroll
        for (int rr = 0; rr < DTR; ++rr) dp += sDt[t][rr] * Wrow[rr];
        float dlt = softplus_fast(dp);
        float uu  = __half2float(u[gidx]);
        float zz  = __half2float(z[gidx]);
        float du  = dlt * uu;
        float y = 0.f;
        #pragma unroll
        for (int s = 0; s < DSTATE; ++s) {
            float a = __expf(dlt * Arow[s]);
            h[s] = h[s] * a + du * sB[t][s];
            y += h[s] * sC[t][s];
        }
        y2h[gidx] = __float2half((y + uu * Dval) * silu_f(zz));
    }
}

// ---------------- LayerNorm over C + transpose to (B,C,L) ----------------
__global__ __launch_bounds__(256)
void ln_kernel(const float* __restrict__ X, const float* __restrict__ gamma,
               const float* __restrict__ beta, float* __restrict__ out)
{
    __shared__ float tile[32][257];
    __shared__ float sMu[32], sRs[32];
    const int l0 = blockIdx.x * 32;
    const int b  = blockIdx.y;
    const int tid = threadIdx.x;
    for (int i = tid; i < 32 * 256; i += 256) {
        int l = i >> 8, c = i & 255;
        tile[l][c] = X[((long)b * L + l0 + l) * CDIM + c];
    }
    __syncthreads();
    {
        int l = tid >> 3, sub = tid & 7;
        float s1 = 0.f, s2 = 0.f;
        for (int c = sub * 32; c < sub * 32 + 32; ++c) {
            float v = tile[l][c];
            s1 += v; s2 += v * v;
        }
        s1 += __shfl_xor(s1, 1); s2 += __shfl_xor(s2, 1);
        s1 += __shfl_xor(s1, 2); s2 += __shfl_xor(s2, 2);
        s1 += __shfl_xor(s1, 4); s2 += __shfl_xor(s2, 4);
        if (sub == 0) {
            float mu = s1 * (1.f / 256.f);
            float var = s2 * (1.f / 256.f) - mu * mu;
            sMu[l] = mu;
            sRs[l] = rsqrtf(var + 1e-5f);
        }
    }
    __syncthreads();
    for (int i = tid; i < 32 * 256; i += 256) {
        int ll = i & 31, c = i >> 5;
        float v = (tile[ll][c] - sMu[ll]) * sRs[ll] * gamma[c] + beta[c];
        out[((long)b * CDIM + c) * L + l0 + ll] = v;
    }
}

extern "C" void kernel_launch(void* const* d_in, const int* in_sizes, int n_in,
                              void* d_out, int out_size, void* d_ws, size_t ws_size,
                              hipStream_t stream)
{
    const float* sp   = (const float*)d_in[0];
    const float* fq   = (const float*)d_in[1];
    const float* Wp   = (const float*)d_in[2];
    const float* bp   = (const float*)d_in[3];
    const float* Win  = (const float*)d_in[4];
    const float* cw   = (const float*)d_in[5];
    const float* cb   = (const float*)d_in[6];
    const float* Wx   = (const float*)d_in[7];
    const float* Wdt  = (const float*)d_in[8];
    const float* bdt  = (const float*)d_in[9];
    const float* Alog = (const float*)d_in[10];
    const float* Dp   = (const float*)d_in[11];
    const float* Wout = (const float*)d_in[12];
    const float* gam  = (const float*)d_in[13];
    const float* bet  = (const float*)d_in[14];
    float* out = (float*)d_out;
    float* ws  = (float*)d_ws;

    const size_t NLD = (size_t)BATCH * L * DIN;   // 8.39M
    const size_t NLC = (size_t)BATCH * L * CDIM;  // 4.19M

    size_t off = 0;
    __half* u16   = (__half*)(ws + off); off += NLD / 2;  // pre-conv u
    __half* u16c  = (__half*)(ws + off); off += NLD / 2;  // post-conv silu(u)
    __half* z16   = (__half*)(ws + off); off += NLD / 2;
    __half* y16   = (__half*)(ws + off); off += NLD / 2;
    __half* xp16  = (__half*)(ws + off); off += NLC / 2;
    float*  xmix  = ws + off; off += NLC;
    float*  dtA   = ws + off; off += (size_t)BATCH * L * DTR;   // raw dt (fp32, 1 MB)
    __half* wph   = (__half*)(ws + off); off += SZ_WP / 2;
    __half* winh  = (__half*)(ws + off); off += SZ_WIN / 2;
    __half* woh   = (__half*)(ws + off); off += SZ_WO / 2;
    __half* wch   = (__half*)(ws + off); off += SZ_WC / 2;
    float*  Bmb   = ws + off; off += (size_t)BATCH * L * DSTATE;
    float*  Cmb   = ws + off; off += (size_t)BATCH * L * DSTATE;
    float*  Asum  = ws + off; off += (size_t)BATCH * NC * DIN * DSTATE;
    float*  Xsum  = ws + off; off += (size_t)BATCH * NC * DIN * DSTATE;

    dim3 blk(256);
    pack_all<<<dim3((SZ_WP + SZ_WIN + SZ_WO + SZ_WC) / 256), blk, 0, stream>>>(
        Wp, Win, Wout, Wx, wph, winh, woh, wch);

    // GEMM1 (fp16): x_proj = x_cat @ Wp^T + bp  (A fp32 K-major; BM=64, NT=2, nBlk=4)
    hgemm<HEPI_XP, true, 2><<<dim3(BATCH * (L/64) * 4), blk, 0, stream>>>(
        sp, fq, nullptr, wph, bp, nullptr, xp16, nullptr, nullptr, nullptr,
        L, CDIM, 2 * CDIM, CDIM, (long)CDIM * L, 4);
    // GEMM2 (fp16): xz = x_proj @ Win^T -> u16 / z16  (BM=64, NT=4, nBlk=8)
    hgemm<HEPI_UZ, false, 4><<<dim3(BATCH * (L/64) * 8), blk, 0, stream>>>(
        nullptr, nullptr, xp16, winh, nullptr, nullptr, u16, z16, nullptr, nullptr,
        L, 2 * DIN, CDIM, 1 << 30, (long)L * CDIM, 8);
    conv_silu_kernel<<<dim3((int)(NLD / 256)), blk, 0, stream>>>(u16, cw, cb, u16c);
    // D34 rank-16 form: dbc = u @ Wx^T (N=48 only: dt|Bm|Cm). delta folded into scans.
    hgemm<HEPI_D34, false, 2><<<dim3(BATCH * (L/64) * 1), blk, 0, stream>>>(
        nullptr, nullptr, u16c, wch, nullptr, dtA, nullptr, nullptr, Bmb, Cmb,
        L, 48, DIN, 1 << 30, (long)L * DIN, 1);

    scan_phase1<<<dim3(BATCH * NC * 2), blk, 0, stream>>>(
        dtA, u16c, Bmb, Alog, Wdt, bdt, Asum, Xsum);
    scan_phase2<<<dim3(BATCH * DIN * DSTATE / 256), blk, 0, stream>>>(Asum, Xsum);
    scan_phase3<<<dim3(BATCH * NC * 2), blk, 0, stream>>>(
        dtA, u16c, Bmb, Cmb, z16, Alog, Wdt, bdt, Dp, Xsum, y16);

    // GEMM5 (fp16): x_mixed = y2 @ Wout^T  (BM=64, NT=2, nBlk=4)
    hgemm<HEPI_F32, false, 2><<<dim3(BATCH * (L/64) * 4), blk, 0, stream>>>(
        nullptr, nullptr, y16, woh, nullptr, xmix, nullptr, nullptr, nullptr, nullptr,
        L, CDIM, DIN, 1 << 30, (long)L * DIN, 4);
    ln_kernel<<<dim3(L / 32, BATCH), blk, 0, stream>>>(xmix, gam, bet, out);
}

// Round 3
// 333.826 us; speedup vs baseline: 1.2299x; 1.0308x over previous
//
#include <hip/hip_runtime.h>
#include <hip/hip_fp16.h>
#include <math.h>

#define L 4096
#define CDIM 256
#define DIN 512
#define DSTATE 16
#define DTR 16
#define BATCH 4

using f32x4  = __attribute__((ext_vector_type(4))) float;
using f16x8  = __attribute__((ext_vector_type(8))) _Float16;

#define LOG2E 1.44269504088896f

#if __has_builtin(__builtin_amdgcn_exp2f)
#define EXP2(x) __builtin_amdgcn_exp2f(x)
#else
#define EXP2(x) __expf((x) * 0.69314718056f)
#endif

__device__ __forceinline__ float silu_f(float x) {
    return __fdividef(x, 1.f + __expf(-x));
}
__device__ __forceinline__ float softplus_fast(float x) {
    return (x > 20.f) ? x : __logf(1.f + __expf(x));
}
__device__ __forceinline__ unsigned pk2h(float a, float b) {
    __half2 h = __floats2half2_rn(a, b);
    return *reinterpret_cast<unsigned*>(&h);
}

#define LDK 40

// ================= fp16 MFMA GEMM: 64-row tiles, double-buffered single-barrier ====
// (Round-0 schedule: measured-good. Do not re-introduce lgkm-only barrier.)
enum { HEPI_XP = 0, HEPI_UZ = 1, HEPI_F32 = 2, HEPI_D34 = 3 };
template<int EPI, bool A_F32KM, int NT>
__global__ __launch_bounds__(256)
void hgemm(const float* __restrict__ Af0, const float* __restrict__ Af1,
           const __half* __restrict__ Ah_g, const __half* __restrict__ Bh_g,
           const float* __restrict__ bias,
           float* __restrict__ O0, __half* __restrict__ Oh0, __half* __restrict__ Oh1,
           float* __restrict__ Ob, float* __restrict__ Oc,
           int M, int N, int K, int kSplit, long strideAb, int nBlk)
{
    constexpr int BM = 64, MT = 2;
    constexpr int BN = 2 * NT * 16;
    constexpr int BSEG = BN / 64;
    __shared__ __align__(16) _Float16 Ah[2][BM][LDK];
    __shared__ __align__(16) _Float16 Bh[2][BN][LDK];
    const int mBlk = M / BM;
    const int bid = blockIdx.x;
    const int r = bid & 7, q = bid >> 3;
    const int ni = q % nBlk;
    const int mg = (q / nBlk) * 8 + r;
    const int b = mg / mBlk, m_idx = mg - b * mBlk;
    const int n0 = ni * BN, m0 = m_idx * BM;
    const int tid  = threadIdx.x;
    const int lane = tid & 63;
    const int w    = tid >> 6;
    const int wr   = w >> 1, wc = w & 1;
    const int lrow = lane & 15;
    const int loct = lane >> 4;

    f32x4 acc[MT][NT];
    #pragma unroll
    for (int i = 0; i < MT; ++i)
        #pragma unroll
        for (int j = 0; j < NT; ++j)
            acc[i][j] = (f32x4){0.f, 0.f, 0.f, 0.f};

    const int sOct = tid & 3, sRow = tid >> 2;
    float va[8];
    uint4 pa, pb[BSEG];

    auto loadA = [&](int kk) {
        if (A_F32KM) {
            int m = tid & 63, ks = tid >> 6;
            #pragma unroll
            for (int j = 0; j < 8; ++j) {
                int kg = kk + ks * 8 + j;
                const float* Ap; int kl;
                if (kg < kSplit) { Ap = Af0; kl = kg; } else { Ap = Af1; kl = kg - kSplit; }
                va[j] = Ap[(long)b * strideAb + (long)kl * M + m0 + m];
            }
        } else {
            pa = *(const uint4*)(Ah_g + (long)b * strideAb +
                                 (long)(m0 + sRow) * K + kk + sOct * 8);
        }
    };
    auto loadB = [&](int kk) {
        #pragma unroll
        for (int p = 0; p < BSEG; ++p) {
            int ng = n0 + sRow + p * 64;
            if (EPI == HEPI_D34 && ng >= N)
                pb[p] = make_uint4(0, 0, 0, 0);
            else
                pb[p] = *(const uint4*)(Bh_g + (long)ng * K + kk + sOct * 8);
        }
    };
    auto storeAB = [&](int buf) {
        if (A_F32KM) {
            int m = tid & 63, ks = tid >> 6;
            uint4 h;
            h.x = pk2h(va[0], va[1]);
            h.y = pk2h(va[2], va[3]);
            h.z = pk2h(va[4], va[5]);
            h.w = pk2h(va[6], va[7]);
            *(uint4*)&Ah[buf][m][ks * 8] = h;
        } else {
            *(uint4*)&Ah[buf][sRow][sOct * 8] = pa;
        }
        #pragma unroll
        for (int p = 0; p < BSEG; ++p)
            *(uint4*)&Bh[buf][sRow + p * 64][sOct * 8] = pb[p];
    };

    loadA(0); loadB(0);
    storeAB(0);
    __syncthreads();
    int cur = 0;
    for (int kk = 0; kk < K; kk += 32) {
        const bool more = (kk + 32 < K);
        if (more) { loadA(kk + 32); loadB(kk + 32); }
        f16x8 bh[NT];
        #pragma unroll
        for (int nt = 0; nt < NT; ++nt)
            bh[nt] = *(const f16x8*)&Bh[cur][wc*NT*16 + nt*16 + lrow][loct*8];
        #pragma unroll
        for (int mt = 0; mt < MT; ++mt) {
            f16x8 ah = *(const f16x8*)&Ah[cur][wr*MT*16 + mt*16 + lrow][loct*8];
            #pragma unroll
            for (int nt = 0; nt < NT; ++nt)
                acc[mt][nt] = __builtin_amdgcn_mfma_f32_16x16x32_f16(ah, bh[nt], acc[mt][nt], 0, 0, 0);
        }
        if (more) {
            storeAB(cur ^ 1);
            __syncthreads();
            cur ^= 1;
        }
    }
    #pragma unroll
    for (int mt = 0; mt < MT; ++mt) {
        #pragma unroll
        for (int r4 = 0; r4 < 4; ++r4) {
            int m = m0 + wr*MT*16 + mt * 16 + loct * 4 + r4;
            long rowb = (long)b * M + m;
            #pragma unroll
            for (int nt = 0; nt < NT; ++nt) {
                int n = n0 + wc*NT*16 + nt * 16 + lrow;
                float v = acc[mt][nt][r4];
                if (EPI == HEPI_XP) {
                    Oh0[rowb * N + n] = __float2half(v + bias[n]);
                } else if (EPI == HEPI_UZ) {
                    if (n < DIN) Oh0[rowb * DIN + n] = __float2half(v);
                    else         Oh1[rowb * DIN + (n - DIN)] = __float2half(v);
                } else if (EPI == HEPI_D34) {
                    if (n < DTR)           O0[rowb * DTR + n] = v;
                    else if (n < 2 * DTR)  Ob[rowb * 16 + (n - DTR)] = v;
                    else if (n < 48)       Oc[rowb * 16 + (n - 32)] = v;
                } else {
                    O0[rowb * N + n] = v;
                }
            }
        }
    }
}

// ---------------- weight prep: fp16 casts ---------
#define SZ_WP  131072
#define SZ_WIN 262144
#define SZ_WO  131072
#define SZ_WC  24576
__global__ __launch_bounds__(256)
void pack_all(const float* __restrict__ Wp, const float* __restrict__ Win,
              const float* __restrict__ Wout, const float* __restrict__ Wx,
              __half* __restrict__ wph, __half* __restrict__ winh,
              __half* __restrict__ woh, __half* __restrict__ wch)
{
    int i = blockIdx.x * 256 + threadIdx.x;
    if (i < SZ_WP) { wph[i] = __float2half(Wp[i]); return; }
    i -= SZ_WP;
    if (i < SZ_WIN) { winh[i] = __float2half(Win[i]); return; }
    i -= SZ_WIN;
    if (i < SZ_WO) { woh[i] = __float2half(Wout[i]); return; }
    i -= SZ_WO;
    if (i < SZ_WC) wch[i] = __float2half(Wx[i]);   // (48, 512) row-major
}

// ---------------- depthwise causal conv (k=4) + silu ---------
__global__ __launch_bounds__(256)
void conv_silu_kernel(const __half* __restrict__ u_pre, const float* __restrict__ cw,
                      const float* __restrict__ cb, __half* __restrict__ u)
{
    long idx = (long)blockIdx.x * blockDim.x + threadIdx.x;
    int d = (int)(idx % DIN);
    long bl = idx / DIN;
    int l = (int)(bl % L);
    long brow = bl - l;
    float v = cb[d];
    #pragma unroll
    for (int j = 0; j < 4; ++j) {
        int li = l - 3 + j;
        if (li >= 0) v += __half2float(u_pre[(brow + li) * DIN + d]) * cw[d * 4 + j];
    }
    u[idx] = __float2half(silu_f(v));
}

// ---------------- chunked parallel selective scan, d-per-lane ----------------
// Latency-oriented rewrite: all per-step inputs staged in LDS (u, z, dt, B, C);
// dp and y dot products tree-reduced (chain 16 -> 4+2); exp via native v_exp_f32
// with log2e pre-folded into Arow; t-loop unroll 2 for cross-step ILP.
#define NC 128
#define LC (L / NC)

__global__ __launch_bounds__(256)
void scan_phase1(const float* __restrict__ dtA, const __half* __restrict__ u,
                 const float* __restrict__ Bm, const float* __restrict__ A_log,
                 const float* __restrict__ Wdt, const float* __restrict__ bdt,
                 float* __restrict__ AX)
{
    __shared__ float sB[LC][DSTATE];
    __shared__ float sDt[LC][DTR];
    __shared__ __half sU[LC][256];
    const int gd = blockIdx.x & 1;
    const int c  = (blockIdx.x >> 1) & (NC - 1);
    const int b  = blockIdx.x >> 8;
    const int tid = threadIdx.x;
    const int d  = gd * 256 + tid;
    const int t0 = c * LC;
    float Arow[DSTATE];
    #pragma unroll
    for (int q = 0; q < 4; ++q) {
        float4 v = *(const float4*)&A_log[d * DSTATE + q * 4];
        Arow[q * 4 + 0] = -__expf(v.x) * LOG2E;
        Arow[q * 4 + 1] = -__expf(v.y) * LOG2E;
        Arow[q * 4 + 2] = -__expf(v.z) * LOG2E;
        Arow[q * 4 + 3] = -__expf(v.w) * LOG2E;
    }
    const float4 W0 = *(const float4*)&Wdt[d * DTR + 0];
    const float4 W1 = *(const float4*)&Wdt[d * DTR + 4];
    const float4 W2 = *(const float4*)&Wdt[d * DTR + 8];
    const float4 W3 = *(const float4*)&Wdt[d * DTR + 12];
    const float bd = bdt[d];
    // stage u (16KB), B (2KB), dt (2KB)
    {
        const __half* ub = u + ((long)b * L + t0) * DIN + gd * 256;
        #pragma unroll
        for (int j = 0; j < 4; ++j) {
            int i = tid + j * 256;            // 1024 float4s
            int t = i >> 5, col = (i & 31) * 8;
            *(float4*)&sU[t][col] = *(const float4*)&ub[(long)t * DIN + col];
        }
        if (tid < 128) {
            const float* Bb = Bm  + ((long)b * L + t0) * DSTATE;
            const float* Db = dtA + ((long)b * L + t0) * DTR;
            *(float4*)&((float*)sB)[tid * 4]  = *(const float4*)&Bb[tid * 4];
            *(float4*)&((float*)sDt)[tid * 4] = *(const float4*)&Db[tid * 4];
        }
    }
    __syncthreads();
    float P[DSTATE], X[DSTATE];
    #pragma unroll
    for (int s = 0; s < DSTATE; ++s) { P[s] = 1.f; X[s] = 0.f; }
    #pragma unroll 2
    for (int t = 0; t < LC; ++t) {
        float4 q0 = *(const float4*)&sDt[t][0];
        float4 q1 = *(const float4*)&sDt[t][4];
        float4 q2 = *(const float4*)&sDt[t][8];
        float4 q3 = *(const float4*)&sDt[t][12];
        float dp0 = fmaf(q0.x, W0.x, fmaf(q0.y, W0.y, fmaf(q0.z, W0.z, q0.w * W0.w)));
        float dp1 = fmaf(q1.x, W1.x, fmaf(q1.y, W1.y, fmaf(q1.z, W1.z, q1.w * W1.w)));
        float dp2 = fmaf(q2.x, W2.x, fmaf(q2.y, W2.y, fmaf(q2.z, W2.z, q2.w * W2.w)));
        float dp3 = fmaf(q3.x, W3.x, fmaf(q3.y, W3.y, fmaf(q3.z, W3.z, q3.w * W3.w)));
        float dlt = softplus_fast(((dp0 + dp1) + (dp2 + dp3)) + bd);
        float du  = dlt * __half2float(sU[t][tid]);
        float Brow[DSTATE];
        *(float4*)&Brow[0]  = *(const float4*)&sB[t][0];
        *(float4*)&Brow[4]  = *(const float4*)&sB[t][4];
        *(float4*)&Brow[8]  = *(const float4*)&sB[t][8];
        *(float4*)&Brow[12] = *(const float4*)&sB[t][12];
        #pragma unroll
        for (int s = 0; s < DSTATE; ++s) {
            float a = EXP2(dlt * Arow[s]);
            P[s] *= a;
            X[s] = fmaf(a, X[s], du * Brow[s]);
        }
    }
    long o2 = ((((long)b * NC + c) * DIN + d) * DSTATE) * 2;
    #pragma unroll
    for (int q = 0; q < 8; ++q)
        *(float4*)&AX[o2 + q * 4] =
            make_float4(P[2*q], X[2*q], P[2*q+1], X[2*q+1]);
}

// cross-chunk scan: 32768 independent series (0.5 waves/SIMD -> pure-ILP kernel).
// float2 interleaved A|X loads, groups of 4, depth-2 group prefetch.
__global__ __launch_bounds__(256)
void scan_phase2(const float* __restrict__ AX, float* __restrict__ Hout)
{
    int lane = blockIdx.x * 256 + threadIdx.x;   // 32768 total
    int b = lane >> 13;
    int rem = lane & 8191;
    const long cs = (long)DIN * DSTATE;          // chunk stride (elements)
    const long base = (long)b * NC * cs + rem;
    float h = 0.f;
    float2 c0, c1, c2, c3, n0, n1, n2, n3;
    auto ld = [&](int c) -> float2 {
        return *(const float2*)&AX[2 * (base + (long)c * cs)];
    };
    c0 = ld(0); c1 = ld(1); c2 = ld(2); c3 = ld(3);
    n0 = ld(4); n1 = ld(5); n2 = ld(6); n3 = ld(7);
    for (int c = 0; c < NC; c += 4) {
        Hout[base + (long)(c+0) * cs] = h; h = fmaf(c0.x, h, c0.y);
        Hout[base + (long)(c+1) * cs] = h; h = fmaf(c1.x, h, c1.y);
        Hout[base + (long)(c+2) * cs] = h; h = fmaf(c2.x, h, c2.y);
        Hout[base + (long)(c+3) * cs] = h; h = fmaf(c3.x, h, c3.y);
        c0 = n0; c1 = n1; c2 = n2; c3 = n3;
        if (c + 8 < NC) { n0 = ld(c+8); n1 = ld(c+9); n2 = ld(c+10); n3 = ld(c+11); }
    }
}

__global__ __launch_bounds__(256)
void scan_phase3(const float* __restrict__ dtA, const __half* __restrict__ u,
                 const float* __restrict__ Bm, const float* __restrict__ Cm,
                 const __half* __restrict__ z, const float* __restrict__ A_log,
                 const float* __restrict__ Wdt, const float* __restrict__ bdt,
                 const float* __restrict__ Dp, const float* __restrict__ Hinit,
                 __half* __restrict__ y2h)
{
    __shared__ float sB[LC][DSTATE], sC[LC][DSTATE];
    __shared__ float sDt[LC][DTR];
    __shared__ __half sU[LC][256];
    __shared__ __half sZ[LC][256];
    const int gd = blockIdx.x & 1;
    const int c  = (blockIdx.x >> 1) & (NC - 1);
    const int b  = blockIdx.x >> 8;
    const int tid = threadIdx.x;
    const int d  = gd * 256 + tid;
    const int t0 = c * LC;
    float Arow[DSTATE];
    #pragma unroll
    for (int q = 0; q < 4; ++q) {
        float4 v = *(const float4*)&A_log[d * DSTATE + q * 4];
        Arow[q * 4 + 0] = -__expf(v.x) * LOG2E;
        Arow[q * 4 + 1] = -__expf(v.y) * LOG2E;
        Arow[q * 4 + 2] = -__expf(v.z) * LOG2E;
        Arow[q * 4 + 3] = -__expf(v.w) * LOG2E;
    }
    const float4 W0 = *(const float4*)&Wdt[d * DTR + 0];
    const float4 W1 = *(const float4*)&Wdt[d * DTR + 4];
    const float4 W2 = *(const float4*)&Wdt[d * DTR + 8];
    const float4 W3 = *(const float4*)&Wdt[d * DTR + 12];
    const float bd = bdt[d];
    // stage u,z (16KB each), B,C,dt (2KB each)
    {
        const __half* ub = u + ((long)b * L + t0) * DIN + gd * 256;
        const __half* zb = z + ((long)b * L + t0) * DIN + gd * 256;
        #pragma unroll
        for (int j = 0; j < 4; ++j) {
            int i = tid + j * 256;
            int t = i >> 5, col = (i & 31) * 8;
            *(float4*)&sU[t][col] = *(const float4*)&ub[(long)t * DIN + col];
            *(float4*)&sZ[t][col] = *(const float4*)&zb[(long)t * DIN + col];
        }
        if (tid < 128) {
            const float* Bb = Bm  + ((long)b * L + t0) * DSTATE;
            const float* Cb = Cm  + ((long)b * L + t0) * DSTATE;
            const float* Db = dtA + ((long)b * L + t0) * DTR;
            *(float4*)&((float*)sB)[tid * 4]  = *(const float4*)&Bb[tid * 4];
            *(float4*)&((float*)sC)[tid * 4]  = *(const float4*)&Cb[tid * 4];
            *(float4*)&((float*)sDt)[tid * 4] = *(const float4*)&Db[tid * 4];
        }
    }
    float h[DSTATE];
    {
        long o = (((long)b * NC + c) * DIN + d) * DSTATE;
        #pragma unroll
        for (int q = 0; q < 4; ++q) {
            float4 v = *(const float4*)&Hinit[o + q * 4];
            h[q * 4 + 0] = v.x; h[q * 4 + 1] = v.y;
            h[q * 4 + 2] = v.z; h[q * 4 + 3] = v.w;
        }
    }
    const float Dval = Dp[d];
    __syncthreads();
    #pragma unroll 2
    for (int t = 0; t < LC; ++t) {
        float4 q0 = *(const float4*)&sDt[t][0];
        float4 q1 = *(const float4*)&sDt[t][4];
        float4 q2 = *(const float4*)&sDt[t][8];
        float4 q3 = *(const float4*)&sDt[t][12];
        float dp0 = fmaf(q0.x, W0.x, fmaf(q0.y, W0.y, fmaf(q0.z, W0.z, q0.w * W0.w)));
        float dp1 = fmaf(q1.x, W1.x, fmaf(q1.y, W1.y, fmaf(q1.z, W1.z, q1.w * W1.w)));
        float dp2 = fmaf(q2.x, W2.x, fmaf(q2.y, W2.y, fmaf(q2.z, W2.z, q2.w * W2.w)));
        float dp3 = fmaf(q3.x, W3.x, fmaf(q3.y, W3.y, fmaf(q3.z, W3.z, q3.w * W3.w)));
        float dlt = softplus_fast(((dp0 + dp1) + (dp2 + dp3)) + bd);
        float uu = __half2float(sU[t][tid]);
        float zz = __half2float(sZ[t][tid]);
        float du = dlt * uu;
        float Brow[DSTATE], Crow[DSTATE];
        *(float4*)&Brow[0]  = *(const float4*)&sB[t][0];
        *(float4*)&Brow[4]  = *(const float4*)&sB[t][4];
        *(float4*)&Brow[8]  = *(const float4*)&sB[t][8];
        *(float4*)&Brow[12] = *(const float4*)&sB[t][12];
        *(float4*)&Crow[0]  = *(const float4*)&sC[t][0];
        *(float4*)&Crow[4]  = *(const float4*)&sC[t][4];
        *(float4*)&Crow[8]  = *(const float4*)&sC[t][8];
        *(float4*)&Crow[12] = *(const float4*)&sC[t][12];
        float y0 = 0.f, y1 = 0.f, y2 = 0.f, y3 = 0.f;
        #pragma unroll
        for (int s = 0; s < DSTATE; s += 4) {
            float a0 = EXP2(dlt * Arow[s+0]);
            float a1 = EXP2(dlt * Arow[s+1]);
            float a2 = EXP2(dlt * Arow[s+2]);
            float a3 = EXP2(dlt * Arow[s+3]);
            h[s+0] = fmaf(h[s+0], a0, du * Brow[s+0]);
            h[s+1] = fmaf(h[s+1], a1, du * Brow[s+1]);
            h[s+2] = fmaf(h[s+2], a2, du * Brow[s+2]);
            h[s+3] = fmaf(h[s+3], a3, du * Brow[s+3]);
            y0 = fmaf(h[s+0], Crow[s+0], y0);
            y1 = fmaf(h[s+1], Crow[s+1], y1);
            y2 = fmaf(h[s+2], Crow[s+2], y2);
            y3 = fmaf(h[s+3], Crow[s+3], y3);
        }
        float y = (y0 + y1) + (y2 + y3);
        long gidx = ((long)b * L + t0 + t) * DIN + d;
        y2h[gidx] = __float2half((y + uu * Dval) * silu_f(zz));
    }
}

// ---------------- LayerNorm over C + transpose to (B,C,L) ----------------
__global__ __launch_bounds__(256)
void ln_kernel(const float* __restrict__ X, const float* __restrict__ gamma,
               const float* __restrict__ beta, float* __restrict__ out)
{
    __shared__ float tile[32][257];
    __shared__ float sMu[32], sRs[32];
    const int l0 = blockIdx.x * 32;
    const int b  = blockIdx.y;
    const int tid = threadIdx.x;
    for (int i = tid; i < 32 * 256; i += 256) {
        int l = i >> 8, c = i & 255;
        tile[l][c] = X[((long)b * L + l0 + l) * CDIM + c];
    }
    __syncthreads();
    {
        int l = tid >> 3, sub = tid & 7;
        float s1 = 0.f, s2 = 0.f;
        for (int c = sub * 32; c < sub * 32 + 32; ++c) {
            float v = tile[l][c];
            s1 += v; s2 += v * v;
        }
        s1 += __shfl_xor(s1, 1); s2 += __shfl_xor(s2, 1);
        s1 += __shfl_xor(s1, 2); s2 += __shfl_xor(s2, 2);
        s1 += __shfl_xor(s1, 4); s2 += __shfl_xor(s2, 4);
        if (sub == 0) {
            float mu = s1 * (1.f / 256.f);
            float var = s2 * (1.f / 256.f) - mu * mu;
            sMu[l] = mu;
            sRs[l] = rsqrtf(var + 1e-5f);
        }
    }
    __syncthreads();
    for (int i = tid; i < 32 * 256; i += 256) {
        int ll = i & 31, c = i >> 5;
        float v = (tile[ll][c] - sMu[ll]) * sRs[ll] * gamma[c] + beta[c];
        out[((long)b * CDIM + c) * L + l0 + ll] = v;
    }
}

extern "C" void kernel_launch(void* const* d_in, const int* in_sizes, int n_in,
                              void* d_out, int out_size, void* d_ws, size_t ws_size,
                              hipStream_t stream)
{
    const float* sp   = (const float*)d_in[0];
    const float* fq   = (const float*)d_in[1];
    const float* Wp   = (const float*)d_in[2];
    const float* bp   = (const float*)d_in[3];
    const float* Win  = (const float*)d_in[4];
    const float* cw   = (const float*)d_in[5];
    const float* cb   = (const float*)d_in[6];
    const float* Wx   = (const float*)d_in[7];
    const float* Wdt  = (const float*)d_in[8];
    const float* bdt  = (const float*)d_in[9];
    const float* Alog = (const float*)d_in[10];
    const float* Dp   = (const float*)d_in[11];
    const float* Wout = (const float*)d_in[12];
    const float* gam  = (const float*)d_in[13];
    const float* bet  = (const float*)d_in[14];
    float* out = (float*)d_out;
    float* ws  = (float*)d_ws;

    const size_t NLD = (size_t)BATCH * L * DIN;   // 8.39M
    const size_t NLC = (size_t)BATCH * L * CDIM;  // 4.19M

    size_t off = 0;
    __half* u16   = (__half*)(ws + off); off += NLD / 2;  // pre-conv u
    __half* u16c  = (__half*)(ws + off); off += NLD / 2;  // post-conv silu(u)
    __half* z16   = (__half*)(ws + off); off += NLD / 2;
    __half* y16   = (__half*)(ws + off); off += NLD / 2;
    __half* xp16  = (__half*)(ws + off); off += NLC / 2;
    float*  xmix  = ws + off; off += NLC;
    float*  dtA   = ws + off; off += (size_t)BATCH * L * DTR;   // raw dt (fp32, 1 MB)
    __half* wph   = (__half*)(ws + off); off += SZ_WP / 2;
    __half* winh  = (__half*)(ws + off); off += SZ_WIN / 2;
    __half* woh   = (__half*)(ws + off); off += SZ_WO / 2;
    __half* wch   = (__half*)(ws + off); off += SZ_WC / 2;
    float*  Bmb   = ws + off; off += (size_t)BATCH * L * DSTATE;
    float*  Cmb   = ws + off; off += (size_t)BATCH * L * DSTATE;
    float*  AX    = ws + off; off += (size_t)BATCH * NC * DIN * DSTATE * 2;
    float*  Hout  = ws + off; off += (size_t)BATCH * NC * DIN * DSTATE;

    dim3 blk(256);
    pack_all<<<dim3((SZ_WP + SZ_WIN + SZ_WO + SZ_WC) / 256), blk, 0, stream>>>(
        Wp, Win, Wout, Wx, wph, winh, woh, wch);

    // GEMM1 (fp16): x_proj = x_cat @ Wp^T + bp
    hgemm<HEPI_XP, true, 2><<<dim3(BATCH * (L/64) * 4), blk, 0, stream>>>(
        sp, fq, nullptr, wph, bp, nullptr, xp16, nullptr, nullptr, nullptr,
        L, CDIM, 2 * CDIM, CDIM, (long)CDIM * L, 4);
    // GEMM2 (fp16): xz = x_proj @ Win^T -> u16 / z16
    hgemm<HEPI_UZ, false, 4><<<dim3(BATCH * (L/64) * 8), blk, 0, stream>>>(
        nullptr, nullptr, xp16, winh, nullptr, nullptr, u16, z16, nullptr, nullptr,
        L, 2 * DIN, CDIM, 1 << 30, (long)L * CDIM, 8);
    conv_silu_kernel<<<dim3((int)(NLD / 256)), blk, 0, stream>>>(u16, cw, cb, u16c);
    // D34 rank-16: dbc = u @ Wx^T (N=48: dt|Bm|Cm). delta folded into scans.
    hgemm<HEPI_D34, false, 2><<<dim3(BATCH * (L/64) * 1), blk, 0, stream>>>(
        nullptr, nullptr, u16c, wch, nullptr, dtA, nullptr, nullptr, Bmb, Cmb,
        L, 48, DIN, 1 << 30, (long)L * DIN, 1);

    scan_phase1<<<dim3(BATCH * NC * 2), blk, 0, stream>>>(
        dtA, u16c, Bmb, Alog, Wdt, bdt, AX);
    scan_phase2<<<dim3(BATCH * DIN * DSTATE / 256), blk, 0, stream>>>(AX, Hout);
    scan_phase3<<<dim3(BATCH * NC * 2), blk, 0, stream>>>(
        dtA, u16c, Bmb, Cmb, z16, Alog, Wdt, bdt, Dp, Hout, y16);

    // GEMM5 (fp16): x_mixed = y2 @ Wout^T
    hgemm<HEPI_F32, false, 2><<<dim3(BATCH * (L/64) * 4), blk, 0, stream>>>(
        nullptr, nullptr, y16, woh, nullptr, xmix, nullptr, nullptr, nullptr, nullptr,
        L, CDIM, DIN, 1 << 30, (long)L * DIN, 4);
    ln_kernel<<<dim3(L / 32, BATCH), blk, 0, stream>>>(xmix, gam, bet, out);
}